// Round 1
// baseline (5658.418 us; speedup 1.0000x reference)
//
#include <hip/hip_runtime.h>
#include <hip/hip_bf16.h>
#include <cstddef>
#include <cstdint>

// Problem constants
#define BB 8
#define SS 1024
#define EE 512
#define DD 1024
#define LL 8
#define HH 16
#define HD 64
#define ROT 32
#define FF 4096
#define FUSED 11264   // 3*D + 2*FF
#define NTOK 8192     // B*S

using u16 = unsigned short;
typedef __attribute__((ext_vector_type(8))) __bf16 bf16x8;
typedef __attribute__((ext_vector_type(4))) float f32x4;
typedef __attribute__((ext_vector_type(4))) unsigned short u16x4;

typedef const __attribute__((address_space(1))) void gas_t;
typedef __attribute__((address_space(3))) void las_t;

__device__ __forceinline__ void gld16(const void* g, void* l) {
  __builtin_amdgcn_global_load_lds((gas_t*)g, (las_t*)l, 16, 0, 0);
}

__device__ __forceinline__ float bf2f(u16 u) {
  union { unsigned int i; float f; } v; v.i = ((unsigned int)u) << 16; return v.f;
}
__device__ __forceinline__ u16 f2bf(float f) {
  union { float f; unsigned int i; } v; v.f = f;
  unsigned int u = v.i;
  unsigned int r = u + 0x7FFFu + ((u >> 16) & 1u);
  return (u16)(r >> 16);
}
__device__ __forceinline__ float gelu_f(float x) {
  return x * 0.5f * (1.0f + erff(x / 1.41421f));
}
__device__ __forceinline__ float silu_f(float x) {
  return x / (1.0f + __expf(-x));
}

// ---------------------------------------------------------------------------
// Generic bf16 B^T GEMM: C[M,N] (+)= A[M,K] * W[N,K]^T (+ bias[N])
// 128x128 tile, BK=64, 4 waves (2x2), mfma_f32_16x16x32_bf16.
// global_load_lds staging with both-sides XOR swizzle (byte ^= (row&7)<<4).
// ---------------------------------------------------------------------------
template <int ACCUM, int OUTBF16>
__global__ __launch_bounds__(256, 2) void gemm_bt(
    const u16* __restrict__ A, const u16* __restrict__ W,
    const float* __restrict__ bias, void* __restrict__ Cp,
    int M, int N, int K) {
  __shared__ __align__(16) u16 As[128 * 64];
  __shared__ __align__(16) u16 Bs[128 * 64];
  const int tid = threadIdx.x;
  const int w = tid >> 6, lane = tid & 63;
  const int m0 = blockIdx.y * 128, n0 = blockIdx.x * 128;
  const int wm = w >> 1, wn = w & 1;

  f32x4 acc[4][4] = {};

  for (int k0 = 0; k0 < K; k0 += 64) {
#pragma unroll
    for (int i = 0; i < 4; i++) {
      const int c = w + i * 4;                 // 1KB chunk id, 0..15
      const int r = c * 8 + (lane >> 3);       // tile row (128B rows)
      const int colb = ((lane & 7) << 4) ^ ((r & 7) << 4);  // pre-swizzled src col (bytes)
      const u16* ga = A + (size_t)(m0 + r) * K + k0 + (colb >> 1);
      gld16(ga, &As[c * 512]);
      const u16* gb = W + (size_t)(n0 + r) * K + k0 + (colb >> 1);
      gld16(gb, &Bs[c * 512]);
    }
    __syncthreads();
#pragma unroll
    for (int ks = 0; ks < 2; ks++) {
      bf16x8 av[4], bv[4];
#pragma unroll
      for (int m = 0; m < 4; m++) {
        const int row = wm * 64 + m * 16 + (lane & 15);
        const int cb = (ks * 64 + ((lane >> 4) << 4)) ^ ((row & 7) << 4);
        av[m] = *(const bf16x8*)((const char*)As + row * 128 + cb);
      }
#pragma unroll
      for (int n = 0; n < 4; n++) {
        const int row = wn * 64 + n * 16 + (lane & 15);
        const int cb = (ks * 64 + ((lane >> 4) << 4)) ^ ((row & 7) << 4);
        bv[n] = *(const bf16x8*)((const char*)Bs + row * 128 + cb);
      }
#pragma unroll
      for (int m = 0; m < 4; m++)
#pragma unroll
        for (int n = 0; n < 4; n++)
          acc[m][n] = __builtin_amdgcn_mfma_f32_16x16x32_bf16(av[m], bv[n], acc[m][n], 0, 0, 0);
    }
    __syncthreads();
  }

  const int colb0 = n0 + wn * 64 + (lane & 15);
  const int rowb0 = m0 + wm * 64 + ((lane >> 4) << 2);
#pragma unroll
  for (int n = 0; n < 4; n++) {
    const int col = colb0 + n * 16;
    const float bn = bias ? bias[col] : 0.0f;
#pragma unroll
    for (int m = 0; m < 4; m++) {
#pragma unroll
      for (int r = 0; r < 4; r++) {
        const size_t idx = (size_t)(rowb0 + m * 16 + r) * N + col;
        const float v = acc[m][n][r] + bn;
        if (ACCUM) {
          ((float*)Cp)[idx] += v;
        } else if (OUTBF16) {
          ((u16*)Cp)[idx] = f2bf(v);
        } else {
          ((float*)Cp)[idx] = v;
        }
      }
    }
  }
}

// ---------------------------------------------------------------------------
// Flash attention. grid (S/64, H, B), 256 threads (4 waves x 16 q-rows).
// qr,kr: (B,H,S,64) bf16 (roped). vt: (B,H,64,S) bf16 (transposed V).
// mask: (B,1,1,S) f32. merged out: (B,S,D) bf16 at [b][s][h*64+d].
// Scores scaled by 1/64 (reference applies sm_scale to BOTH q and k).
// ---------------------------------------------------------------------------
__global__ __launch_bounds__(256, 2) void attn_fwd(
    const u16* __restrict__ qr, const u16* __restrict__ kr,
    const u16* __restrict__ vt, const float* __restrict__ mask,
    u16* __restrict__ merged) {
  __shared__ __align__(16) u16 Ks[128 * 64];   // [key][dim]
  __shared__ __align__(16) u16 Vs[64 * 128];   // [d][key]
  __shared__ __align__(16) u16 Ps[4][16 * 144];  // per-wave P, padded rows (288B)
  const int tid = threadIdx.x, w = tid >> 6, lane = tid & 63;
  const int b = blockIdx.z, hh = blockIdx.y;
  const int q0 = blockIdx.x * 64 + w * 16;
  const size_t bh = (size_t)b * HH + hh;
  const u16* Qb = qr + bh * SS * HD;
  const u16* Kb = kr + bh * SS * HD;
  const u16* Vb = vt + bh * HD * SS;
  const float* mb = mask + (size_t)b * SS;

  bf16x8 qf0, qf1;
  {
    const int qrow = q0 + (lane & 15);
    const u16* qp = Qb + (size_t)qrow * HD + ((lane >> 4) << 3);
    qf0 = *(const bf16x8*)qp;
    qf1 = *(const bf16x8*)(qp + 32);
  }

  float mrun[4], srun[4];
  f32x4 acc[4] = {};
#pragma unroll
  for (int r = 0; r < 4; r++) { mrun[r] = -1e30f; srun[r] = 0.0f; }

  for (int t = 0; t < 8; t++) {
    const int kv0 = t * 128;
#pragma unroll
    for (int i = 0; i < 4; i++) {
      const int c = w + i * 4;
      {  // K chunk (rows of 128B, 8 rows/KB)
        const int r = c * 8 + (lane >> 3);
        const int colb = ((lane & 7) << 4) ^ ((r & 7) << 4);
        gld16(Kb + (size_t)(kv0 + r) * HD + (colb >> 1), &Ks[c * 512]);
      }
      {  // V chunk (rows of 256B, 4 rows/KB)
        const int d = c * 4 + (lane >> 4);
        const int colb = ((lane & 15) << 4) ^ ((d & 7) << 4);
        gld16(Vb + (size_t)d * SS + kv0 + (colb >> 1), &Vs[c * 512]);
      }
    }
    __syncthreads();

    // QK^T: D[q][key], 8 key-blocks x 2 dim-chunks
    f32x4 p[8];
#pragma unroll
    for (int blk = 0; blk < 8; blk++) {
      const int row = blk * 16 + (lane & 15);
      const int swz = (row & 7) << 4;
      const bf16x8 k0v = *(const bf16x8*)((const char*)Ks + row * 128 + ((((lane >> 4) << 4)) ^ swz));
      const bf16x8 k1v = *(const bf16x8*)((const char*)Ks + row * 128 + ((64 + ((lane >> 4) << 4)) ^ swz));
      f32x4 z = {};
      p[blk] = __builtin_amdgcn_mfma_f32_16x16x32_bf16(qf0, k0v, z, 0, 0, 0);
      p[blk] = __builtin_amdgcn_mfma_f32_16x16x32_bf16(qf1, k1v, p[blk], 0, 0, 0);
    }

    float mv[8];
#pragma unroll
    for (int blk = 0; blk < 8; blk++) mv[blk] = mb[kv0 + blk * 16 + (lane & 15)];
#pragma unroll
    for (int blk = 0; blk < 8; blk++)
#pragma unroll
      for (int r = 0; r < 4; r++) p[blk][r] = p[blk][r] * (1.0f / 64.0f) + mv[blk];

    // online softmax per q-row (reduce across the 16-lane group)
    float fac[4];
#pragma unroll
    for (int r = 0; r < 4; r++) {
      float tm = p[0][r];
#pragma unroll
      for (int blk = 1; blk < 8; blk++) tm = fmaxf(tm, p[blk][r]);
      tm = fmaxf(tm, __shfl_xor(tm, 1));
      tm = fmaxf(tm, __shfl_xor(tm, 2));
      tm = fmaxf(tm, __shfl_xor(tm, 4));
      tm = fmaxf(tm, __shfl_xor(tm, 8));
      const float mn = fmaxf(mrun[r], tm);
      fac[r] = __expf(mrun[r] - mn);
      mrun[r] = mn;
      float rs = 0.0f;
#pragma unroll
      for (int blk = 0; blk < 8; blk++) {
        const float e = __expf(p[blk][r] - mn);
        p[blk][r] = e;
        rs += e;
      }
      rs += __shfl_xor(rs, 1);
      rs += __shfl_xor(rs, 2);
      rs += __shfl_xor(rs, 4);
      rs += __shfl_xor(rs, 8);
      srun[r] = srun[r] * fac[r] + rs;
    }
#pragma unroll
    for (int dblk = 0; dblk < 4; dblk++)
#pragma unroll
      for (int r = 0; r < 4; r++) acc[dblk][r] *= fac[r];

    // write P (bf16) to per-wave LDS, then PV
    u16* pw = &Ps[w][0];
#pragma unroll
    for (int blk = 0; blk < 8; blk++)
#pragma unroll
      for (int r = 0; r < 4; r++)
        pw[(((lane >> 4) << 2) + r) * 144 + blk * 16 + (lane & 15)] = f2bf(p[blk][r]);

    bf16x8 pa[4];
#pragma unroll
    for (int ks = 0; ks < 4; ks++)
      pa[ks] = *(const bf16x8*)(pw + (lane & 15) * 144 + ks * 32 + ((lane >> 4) << 3));
#pragma unroll
    for (int dblk = 0; dblk < 4; dblk++) {
      const int drow = dblk * 16 + (lane & 15);
      const int swz = (drow & 7) << 4;
#pragma unroll
      for (int ks = 0; ks < 4; ks++) {
        const bf16x8 vv = *(const bf16x8*)((const char*)Vs + drow * 256 + ((ks * 64 + ((lane >> 4) << 4)) ^ swz));
        acc[dblk] = __builtin_amdgcn_mfma_f32_16x16x32_bf16(pa[ks], vv, acc[dblk], 0, 0, 0);
      }
    }
    __syncthreads();
  }

#pragma unroll
  for (int dblk = 0; dblk < 4; dblk++)
#pragma unroll
    for (int r = 0; r < 4; r++) {
      const int sq = q0 + ((lane >> 4) << 2) + r;
      const int d = dblk * 16 + (lane & 15);
      merged[((size_t)b * SS + sq) * DD + hh * HD + d] = f2bf(acc[dblk][r] / srun[r]);
    }
}

// ---------------------------------------------------------------------------
// LayerNorm (+ optional AdaLN modulation) over D=1024, one block per row.
// out bf16.  sb (may be null): per-batch [scale(1024), bias(1024)].
// ---------------------------------------------------------------------------
__global__ __launch_bounds__(256) void ln_mod(
    const float* __restrict__ x, const float* __restrict__ lw,
    const float* __restrict__ lb, const float* __restrict__ sb,
    u16* __restrict__ out) {
  const int row = blockIdx.x, tid = threadIdx.x;
  const float4 v = ((const float4*)(x + (size_t)row * DD))[tid];
  float vv[4] = {v.x, v.y, v.z, v.w};
  float s = vv[0] + vv[1] + vv[2] + vv[3];
  float q = vv[0] * vv[0] + vv[1] * vv[1] + vv[2] * vv[2] + vv[3] * vv[3];
  for (int off = 1; off < 64; off <<= 1) {
    s += __shfl_xor(s, off);
    q += __shfl_xor(q, off);
  }
  __shared__ float red[8];
  const int w = tid >> 6, lane = tid & 63;
  if (lane == 0) { red[w] = s; red[4 + w] = q; }
  __syncthreads();
  s = red[0] + red[1] + red[2] + red[3];
  q = red[4] + red[5] + red[6] + red[7];
  const float mu = s * (1.0f / DD);
  const float inv = rsqrtf(q * (1.0f / DD) - mu * mu + 1e-5f);
  const int b = row >> 10;  // row = b*S + s
  u16x4 o;
#pragma unroll
  for (int j = 0; j < 4; j++) {
    const int d = tid * 4 + j;
    float g = (vv[j] - mu) * inv * lw[d] + lb[d];
    if (sb) g = (1.0f + sb[(size_t)b * 2048 + d]) * g + sb[(size_t)b * 2048 + DD + d];
    o[j] = f2bf(g);
  }
  *(u16x4*)(out + (size_t)row * DD + tid * 4) = o;
}

// Final LayerNorm over E=512, f32 out. One block (128 threads) per row.
__global__ __launch_bounds__(128) void ln_fin(
    const float* __restrict__ x, const float* __restrict__ w_,
    const float* __restrict__ b_, float* __restrict__ out) {
  const int row = blockIdx.x, tid = threadIdx.x;
  const float4 v = ((const float4*)(x + (size_t)row * EE))[tid];
  float vv[4] = {v.x, v.y, v.z, v.w};
  float s = vv[0] + vv[1] + vv[2] + vv[3];
  float q = vv[0] * vv[0] + vv[1] * vv[1] + vv[2] * vv[2] + vv[3] * vv[3];
  for (int off = 1; off < 64; off <<= 1) {
    s += __shfl_xor(s, off);
    q += __shfl_xor(q, off);
  }
  __shared__ float red[4];
  const int w = tid >> 6, lane = tid & 63;
  if (lane == 0) { red[w] = s; red[2 + w] = q; }
  __syncthreads();
  s = red[0] + red[1];
  q = red[2] + red[3];
  const float mu = s * (1.0f / EE);
  const float inv = rsqrtf(q * (1.0f / EE) - mu * mu + 1e-5f);
  float4 o;
  o.x = (vv[0] - mu) * inv * w_[tid * 4 + 0] + b_[tid * 4 + 0];
  o.y = (vv[1] - mu) * inv * w_[tid * 4 + 1] + b_[tid * 4 + 1];
  o.z = (vv[2] - mu) * inv * w_[tid * 4 + 2] + b_[tid * 4 + 2];
  o.w = (vv[3] - mu) * inv * w_[tid * 4 + 3] + b_[tid * 4 + 3];
  ((float4*)(out + (size_t)row * EE))[tid] = o;
}

// Small f32 GEMM for the time-embedding path: out[l,b,n] = OA(sum_k IA(in[b,k])*W[l,n,k] + bias[l,n])
template <int IA, int OA>
__global__ __launch_bounds__(256) void vec_gemm(
    const float* __restrict__ in, const float* __restrict__ W,
    const float* __restrict__ bias, float* __restrict__ out, int N, int K) {
  const int n = blockIdx.x * 256 + threadIdx.x;
  const int b = blockIdx.y, l = blockIdx.z;
  const float* ir = in + (size_t)b * K;
  const float* wr = W + ((size_t)l * N + n) * K;
  float s = bias[(size_t)l * N + n];
  for (int k = 0; k < K; k += 4) {
    float4 a = *(const float4*)(ir + k);
    const float4 ww = *(const float4*)(wr + k);
    if (IA) { a.x = silu_f(a.x); a.y = silu_f(a.y); a.z = silu_f(a.z); a.w = silu_f(a.w); }
    s += a.x * ww.x + a.y * ww.y + a.z * ww.z + a.w * ww.w;
  }
  if (OA) s = gelu_f(s);
  out[((size_t)l * gridDim.y + b) * N + n] = s;
}

__global__ void time_fourier(const float* __restrict__ times,
                             const float* __restrict__ fw, float* __restrict__ te0) {
  const int j = blockIdx.x * 256 + threadIdx.x;  // 0..511
  const int b = blockIdx.y;
  const float f = 6.28318530717958647692f * times[b] * fw[j];
  te0[(size_t)b * DD + j] = cosf(f);
  te0[(size_t)b * DD + 512 + j] = sinf(f);
}

__global__ void rope_tab(float* __restrict__ st, float* __restrict__ ct) {
  const int s = blockIdx.x;
  const int j = threadIdx.x;  // 0..31
  const int i = j & 15;
  const float inv = powf(10000.0f, -(float)i * (1.0f / 16.0f));
  const float f = (float)s * inv;
  st[s * 32 + j] = bf2f(f2bf(sinf(f)));
  ct[s * 32 + j] = bf2f(f2bf(cosf(f)));
}

// Build bf16 input x = concat(noisy, cond, prev, infill-broadcast) (B,S,2048)
__global__ void build_x(const float* __restrict__ a, const float* __restrict__ b,
                        const float* __restrict__ c, const float* __restrict__ m,
                        u16* __restrict__ x) {
  const size_t i4 = ((size_t)blockIdx.x * 256 + threadIdx.x) * 4;
  if (i4 >= (size_t)NTOK * 2048) return;
  const size_t tok = i4 >> 11;
  const int e = (int)(i4 & 2047);
  float4 v;
  if (e < 512)       v = *(const float4*)(a + tok * 512 + e);
  else if (e < 1024) v = *(const float4*)(b + tok * 512 + (e - 512));
  else if (e < 1536) v = *(const float4*)(c + tok * 512 + (e - 1024));
  else { const float mm = m[tok]; v = make_float4(mm, mm, mm, mm); }
  u16x4 o;
  o[0] = f2bf(v.x); o[1] = f2bf(v.y); o[2] = f2bf(v.z); o[3] = f2bf(v.w);
  *(u16x4*)(x + i4) = o;
}

// RoPE on q,k (first 32 dims/head) + head-split; also emits transposed V.
__global__ void rope_apply(const u16* __restrict__ proj, const float* __restrict__ st,
                           const float* __restrict__ ct, u16* __restrict__ q,
                           u16* __restrict__ k, u16* __restrict__ v) {
  const size_t idx = (size_t)blockIdx.x * 256 + threadIdx.x;  // over B*S*1024
  const size_t tok = idx >> 10;
  const int hd = (int)(idx & 1023);
  const int hh = hd >> 6, d = hd & 63;
  const int s = (int)(tok & 1023);
  const size_t bb = tok >> 10;
  const u16* pr = proj + tok * FUSED;
  float qv = bf2f(pr[hd]);
  float kv = bf2f(pr[DD + hd]);
  const float vv = bf2f(pr[2 * DD + hd]);
  if (d < ROT) {
    const float cs = ct[s * 32 + d], sn = st[s * 32 + d];
    const int pidx = hd - d + ((d < 16) ? d + 16 : d - 16);
    const float qp = bf2f(pr[pidx]);
    const float kp = bf2f(pr[DD + pidx]);
    const float sg = (d < 16) ? -1.0f : 1.0f;
    qv = qv * cs + sg * qp * sn;
    kv = kv * cs + sg * kp * sn;
  }
  const size_t o = ((bb * HH + hh) * SS + s) * HD + d;
  q[o] = f2bf(qv);
  k[o] = f2bf(kv);
  v[((bb * HH + hh) * HD + d) * SS + s] = f2bf(vv);
}

// ffact = ff * gelu(ff_gate)
__global__ void gate_k(const u16* __restrict__ proj, u16* __restrict__ ff) {
  const size_t idx = (size_t)blockIdx.x * 256 + threadIdx.x;  // over B*S*4096
  const size_t tok = idx >> 12;
  const int f = (int)(idx & 4095);
  const u16* pr = proj + tok * FUSED + 3 * DD;
  const float a = bf2f(pr[f]);
  const float g = bf2f(pr[FF + f]);
  ff[idx] = f2bf(a * gelu_f(g));
}

__global__ void cast_bf16(const float* __restrict__ in, u16* __restrict__ out, size_t n4) {
  const size_t i = (size_t)blockIdx.x * 256 + threadIdx.x;
  if (i >= n4) return;
  const float4 v = ((const float4*)in)[i];
  u16x4 o;
  o[0] = f2bf(v.x); o[1] = f2bf(v.y); o[2] = f2bf(v.z); o[3] = f2bf(v.w);
  ((u16x4*)out)[i] = o;
}

// ---------------------------------------------------------------------------
extern "C" void kernel_launch(void* const* d_in, const int* in_sizes, int n_in,
                              void* d_out, int out_size, void* d_ws, size_t ws_size,
                              hipStream_t stream) {
  const float* noisy   = (const float*)d_in[0];
  const float* condi   = (const float*)d_in[1];
  const float* prev    = (const float*)d_in[2];
  const float* infill  = (const float*)d_in[3];
  const float* amask   = (const float*)d_in[4];
  const float* times   = (const float*)d_in[5];
  const float* fourier = (const float*)d_in[6];
  const float* t1_w    = (const float*)d_in[7];
  const float* t1_b    = (const float*)d_in[8];
  const float* t2_w    = (const float*)d_in[9];
  const float* t2_b    = (const float*)d_in[10];
  const float* in_w    = (const float*)d_in[11];
  const float* in_b    = (const float*)d_in[12];
  const float* ln_w    = (const float*)d_in[13];
  const float* ln_b    = (const float*)d_in[14];
  const float* cond_w  = (const float*)d_in[15];
  const float* cond_b  = (const float*)d_in[16];
  const float* proj_w  = (const float*)d_in[17];
  const float* attn_w  = (const float*)d_in[18];
  const float* attn_b  = (const float*)d_in[19];
  const float* ff_w    = (const float*)d_in[20];
  const float* ff_b    = (const float*)d_in[21];
  const float* outln_w = (const float*)d_in[22];
  const float* outln_b = (const float*)d_in[23];
  const float* out_w   = (const float*)d_in[24];
  const float* out_b   = (const float*)d_in[25];
  const float* fin_w   = (const float*)d_in[26];
  const float* fin_b   = (const float*)d_in[27];
  float* outp = (float*)d_out;

  char* p = (char*)d_ws;
  auto alloc = [&](size_t bytes) -> char* {
    char* r = p;
    p += (bytes + 255) & ~(size_t)255;
    return r;
  };
  u16* in_w_h   = (u16*)alloc((size_t)DD * 2048 * 2);
  u16* proj_w_h = (u16*)alloc((size_t)LL * FUSED * DD * 2);
  u16* attn_w_h = (u16*)alloc((size_t)LL * DD * DD * 2);
  u16* ff_w_h   = (u16*)alloc((size_t)LL * DD * FF * 2);
  u16* out_w_h  = (u16*)alloc((size_t)EE * DD * 2);
  float* te0 = (float*)alloc((size_t)BB * DD * 4);
  float* te1 = (float*)alloc((size_t)BB * DD * 4);
  float* te2 = (float*)alloc((size_t)BB * DD * 4);
  float* sb  = (float*)alloc((size_t)LL * BB * 2048 * 4);
  float* stab = (float*)alloc((size_t)SS * 32 * 4);
  float* ctab = (float*)alloc((size_t)SS * 32 * 4);
  u16* xb    = (u16*)alloc((size_t)NTOK * 2048 * 2);
  float* h   = (float*)alloc((size_t)NTOK * DD * 4);
  u16* units = (u16*)alloc((size_t)NTOK * DD * 2);
  u16* projb = (u16*)alloc((size_t)NTOK * FUSED * 2);
  u16* qrb   = (u16*)alloc((size_t)NTOK * DD * 2);
  u16* krb   = (u16*)alloc((size_t)NTOK * DD * 2);
  u16* vtb   = (u16*)alloc((size_t)NTOK * DD * 2);
  u16* mg    = (u16*)alloc((size_t)NTOK * DD * 2);
  u16* ffa   = (u16*)alloc((size_t)NTOK * FF * 2);
  u16* hn    = (u16*)alloc((size_t)NTOK * DD * 2);
  float* ob  = (float*)alloc((size_t)NTOK * EE * 4);

  auto castN = [&](const float* src, u16* dst, size_t n) {
    const size_t n4 = n / 4;
    cast_bf16<<<dim3((unsigned)((n4 + 255) / 256)), dim3(256), 0, stream>>>(src, dst, n4);
  };
  castN(in_w, in_w_h, (size_t)DD * 2048);
  castN(proj_w, proj_w_h, (size_t)LL * FUSED * DD);
  castN(attn_w, attn_w_h, (size_t)LL * DD * DD);
  castN(ff_w, ff_w_h, (size_t)LL * DD * FF);
  castN(out_w, out_w_h, (size_t)EE * DD);

  time_fourier<<<dim3(2, BB), 256, 0, stream>>>(times, fourier, te0);
  vec_gemm<0, 1><<<dim3(4, BB, 1), 256, 0, stream>>>(te0, t1_w, t1_b, te1, 1024, 1024);
  vec_gemm<0, 0><<<dim3(4, BB, 1), 256, 0, stream>>>(te1, t2_w, t2_b, te2, 1024, 1024);
  vec_gemm<1, 0><<<dim3(8, BB, LL), 256, 0, stream>>>(te2, cond_w, cond_b, sb, 2048, 1024);
  rope_tab<<<SS, 32, 0, stream>>>(stab, ctab);
  build_x<<<16384, 256, 0, stream>>>(noisy, condi, prev, infill, xb);
  gemm_bt<0, 0><<<dim3(DD / 128, NTOK / 128), 256, 0, stream>>>(xb, in_w_h, in_b, h, NTOK, DD, 2048);

  for (int l = 0; l < LL; l++) {
    ln_mod<<<NTOK, 256, 0, stream>>>(h, ln_w + (size_t)l * DD, ln_b + (size_t)l * DD,
                                     sb + (size_t)l * BB * 2048, units);
    gemm_bt<0, 1><<<dim3(FUSED / 128, NTOK / 128), 256, 0, stream>>>(
        units, proj_w_h + (size_t)l * FUSED * DD, nullptr, projb, NTOK, FUSED, DD);
    rope_apply<<<32768, 256, 0, stream>>>(projb, stab, ctab, qrb, krb, vtb);
    gate_k<<<131072, 256, 0, stream>>>(projb, ffa);
    attn_fwd<<<dim3(SS / 64, HH, BB), 256, 0, stream>>>(qrb, krb, vtb, amask, mg);
    gemm_bt<1, 0><<<dim3(DD / 128, NTOK / 128), 256, 0, stream>>>(
        mg, attn_w_h + (size_t)l * DD * DD, attn_b + (size_t)l * DD, h, NTOK, DD, DD);
    gemm_bt<1, 0><<<dim3(DD / 128, NTOK / 128), 256, 0, stream>>>(
        ffa, ff_w_h + (size_t)l * DD * FF, ff_b + (size_t)l * DD, h, NTOK, DD, FF);
  }

  ln_mod<<<NTOK, 256, 0, stream>>>(h, outln_w, outln_b, nullptr, hn);
  gemm_bt<0, 0><<<dim3(EE / 128, NTOK / 128), 256, 0, stream>>>(hn, out_w_h, out_b, ob, NTOK, EE, DD);
  ln_fin<<<NTOK, 128, 0, stream>>>(ob, fin_w, fin_b, outp);
}